// Round 5
// baseline (531.202 us; speedup 1.0000x reference)
//
#include <hip/hip_runtime.h>
#include <hip/hip_bf16.h>
#include <math.h>

typedef __attribute__((ext_vector_type(8))) short short8;
typedef __attribute__((ext_vector_type(4))) short short4_t;
typedef __attribute__((ext_vector_type(4))) float f32x4;

#define Bb 2
#define Tt 2048
#define Hh 16
#define Dd 128
#define Cc 2048
#define Ff 6144

__device__ __forceinline__ void gload_lds16(const void* g, void* l) {
  __builtin_amdgcn_global_load_lds(
      (const __attribute__((address_space(1))) void*)g,
      (__attribute__((address_space(3))) void*)l, 16, 0, 0);
}

// fp32 -> bf16 cast, 4 elements/thread, vectorized.
__global__ __launch_bounds__(256) void cast_f32_bf16(
    const float* __restrict__ in, __hip_bfloat16* __restrict__ out, int n4)
{
  int i = blockIdx.x * 256 + threadIdx.x;
  if (i >= n4) return;
  float4 v = ((const float4*)in)[i];
  __hip_bfloat16 tmp[4] = {__float2bfloat16(v.x), __float2bfloat16(v.y),
                           __float2bfloat16(v.z), __float2bfloat16(v.w)};
  ((short4_t*)out)[i] = *(const short4_t*)tmp;
}

__device__ __forceinline__ void store_out(__hip_bfloat16* p, float v) { *p = __float2bfloat16(v); }
__device__ __forceinline__ void store_out(float* p, float v) { *p = v; }

// C (MxN) = A (MxK row-major) * B^T (B NxK row-major). bf16 in, fp32 accum.
// 128x128x64 tile. LDS in fragment-granule order: granule g2 (0..15) =
// row-group (g2>>1)*16..+15, k-half (g2&1)*32..+31; within granule lane l
// holds [scol=l>>4][srow=l&15] 16B — so every MFMA fragment ds_read_b128 is
// granule_base + lane*16B (conflict-free), and global_load_lds's lane*16 dest
// mapping is exactly this layout.
template <typename OutT>
__global__ __launch_bounds__(256) void gemm_bt(
    const __hip_bfloat16* __restrict__ A,
    const __hip_bfloat16* __restrict__ Bm,
    OutT* __restrict__ Cm,
    int K, int N)
{
  __shared__ __align__(16) __hip_bfloat16 As[128 * 64];
  __shared__ __align__(16) __hip_bfloat16 Bs[128 * 64];
  const int tid  = threadIdx.x;
  const int wave = tid >> 6;
  const int lane = tid & 63;
  const int quad = lane >> 4;
  const int l16  = lane & 15;
  const int bm = blockIdx.y * 128;
  const int bn = blockIdx.x * 128;
  const int wm4 = (wave >> 1) * 4;   // row-group base of this wave's M range
  const int wn4 = (wave & 1) * 4;    // row-group base of this wave's N range

  f32x4 acc[4][4];
#pragma unroll
  for (int i = 0; i < 4; i++)
#pragma unroll
    for (int j = 0; j < 4; j++)
#pragma unroll
      for (int r = 0; r < 4; r++) acc[i][j][r] = 0.f;

  const int srow = lane & 15;          // staging: row within 16-row group
  const int scolB = (lane >> 4) * 16;  // staging: byte sub-column within 64B half-row

  for (int k0 = 0; k0 < K; k0 += 64) {
#pragma unroll
    for (int c = 0; c < 4; c++) {
      int g2 = wave * 4 + c;                 // wave-uniform granule id 0..15
      int rg = g2 >> 1, half = g2 & 1;
      const char* srcA = (const char*)A +
          ((size_t)(bm + rg * 16 + srow) * K + k0 + half * 32) * 2 + scolB;
      const char* srcB = (const char*)Bm +
          ((size_t)(bn + rg * 16 + srow) * K + k0 + half * 32) * 2 + scolB;
      gload_lds16(srcA, As + g2 * 512);
      gload_lds16(srcB, Bs + g2 * 512);
    }
    __syncthreads();
#pragma unroll
    for (int ks = 0; ks < 2; ks++) {
      short8 af[4], bf[4];
#pragma unroll
      for (int i = 0; i < 4; i++)
        af[i] = *(const short8*)(As + ((wm4 + i) * 2 + ks) * 512 + lane * 8);
#pragma unroll
      for (int j = 0; j < 4; j++)
        bf[j] = *(const short8*)(Bs + ((wn4 + j) * 2 + ks) * 512 + lane * 8);
#pragma unroll
      for (int i = 0; i < 4; i++)
#pragma unroll
        for (int j = 0; j < 4; j++)
          acc[i][j] = __builtin_amdgcn_mfma_f32_16x16x32_bf16(af[i], bf[j], acc[i][j], 0, 0, 0);
    }
    __syncthreads();
  }

#pragma unroll
  for (int i = 0; i < 4; i++)
#pragma unroll
    for (int j = 0; j < 4; j++)
#pragma unroll
      for (int r = 0; r < 4; r++) {
        int gm = bm + (wave >> 1) * 64 + i * 16 + quad * 4 + r;
        int gn = bn + (wave & 1) * 64 + j * 16 + l16;
        store_out(Cm + (size_t)gm * N + gn, acc[i][j][r]);
      }
}

// In-place RoPE on q,k halves of qkv. Q half additionally pre-scaled by 1/sqrt(D)
// so the flash kernel needs no per-score multiply.
__global__ __launch_bounds__(256) void rope_qk(__hip_bfloat16* __restrict__ qkv)
{
  int tid = blockIdx.x * 256 + threadIdx.x;
  int d = tid & 63;
  int h = (tid >> 6) & 15;
  int t = (tid >> 10) & 2047;
  int bw = tid >> 21;
  int b = bw & 1, which = bw >> 1;
  size_t base = (size_t)(b * Tt + t) * Ff + which * 2048 + h * Dd + d;
  float inv = expf(-(float)d * (9.210340371976184f / 64.0f));
  float ang = (float)t * inv;
  float c = cosf(ang), s = sinf(ang);
  float x1 = __bfloat162float(qkv[base]);
  float x2 = __bfloat162float(qkv[base + 64]);
  float o1 = x1 * c - x2 * s;
  float o2 = x2 * c + x1 * s;
  if (which == 0) {  // q: fold in softmax scale
    o1 *= 0.08838834764831845f;
    o2 *= 0.08838834764831845f;
  }
  qkv[base]      = __float2bfloat16(o1);
  qkv[base + 64] = __float2bfloat16(o2);
}

// v (from qkv buffer, (b,t,h,d)) -> vt (b,h,d,t).
__global__ __launch_bounds__(256) void transpose_v(
    const __hip_bfloat16* __restrict__ qkv, __hip_bfloat16* __restrict__ vt)
{
  __shared__ __hip_bfloat16 tile[64 * 65];
  int bh = blockIdx.y;
  int dt = blockIdx.x >> 5;
  int tt = blockIdx.x & 31;
  int b = bh >> 4, h = bh & 15;
  const __hip_bfloat16* src = qkv + (size_t)(b * Tt + tt * 64) * Ff + 4096 + h * Dd + dt * 64;
#pragma unroll
  for (int i = 0; i < 16; i++) {
    int lin = i * 256 + threadIdx.x;
    int tl = lin >> 6, dc = lin & 63;
    tile[tl * 65 + dc] = src[(size_t)tl * Ff + dc];
  }
  __syncthreads();
  __hip_bfloat16* dst = vt + ((size_t)bh * Dd + dt * 64) * Tt + tt * 64;
#pragma unroll
  for (int i = 0; i < 16; i++) {
    int lin = i * 256 + threadIdx.x;
    int dr = lin >> 6, tc = lin & 63;
    dst[(size_t)dr * Tt + tc] = tile[tc * 65 + dr];
  }
}

// Flash attention v3: 512 threads (8 waves, 16 q-rows each -> 2 waves/SIMD),
// 128-row Q tiles, paired causal scheduling {p, 15-p}, software-pipelined
// staging with raw s_barrier + manual vmcnt.
__global__ __launch_bounds__(512) void flash_attn3(
    const __hip_bfloat16* __restrict__ qkv,
    const __hip_bfloat16* __restrict__ vt,
    __hip_bfloat16* __restrict__ yat)
{
  __shared__ __align__(16) __hip_bfloat16 KsBuf[2][8192];
  __shared__ __align__(16) __hip_bfloat16 VsBuf[8192];
  __shared__ __align__(16) __hip_bfloat16 PsBuf[8 * 1088];
  const int tid  = threadIdx.x;
  const int wave = tid >> 6;          // 0..7
  const int lane = tid & 63;
  const int quad = lane >> 4;
  const int l16  = lane & 15;
  const int bh    = blockIdx.x & 31;
  const int pairp = blockIdx.x >> 5;  // 0..7
  const int b = bh >> 4, h = bh & 15;

  const char* kbase = (const char*)(qkv + (size_t)b * Tt * Ff + 2048 + h * Dd);
  const char* vbase = (const char*)(vt + (size_t)bh * Dd * Tt);
  __hip_bfloat16* Pw = PsBuf + wave * 1088;
  const int srow = lane & 15;
  const int scol = lane >> 4;

#pragma unroll 1
  for (int half = 0; half < 2; ++half) {
    const int qi = half ? (15 - pairp) : pairp;
    const int qm0 = qi * 128;
    const int niter = 2 * qi + 2;

    short8 qf[4];
    {
      const __hip_bfloat16* qrow =
          qkv + (size_t)(b * Tt + qm0 + wave * 16 + l16) * Ff + h * Dd;
#pragma unroll
      for (int kc = 0; kc < 4; kc++)
        qf[kc] = *(const short8*)(qrow + kc * 32 + quad * 8);
    }

#pragma unroll
    for (int c = 0; c < 2; c++) {
      int chunk = wave * 2 + c;
      int j = chunk >> 2, kc = chunk & 3;
      const char* src = kbase + (size_t)(j * 16 + srow) * (Ff * 2) + kc * 64 + scol * 16;
      gload_lds16(src, KsBuf[0] + chunk * 512);
    }

    f32x4 oacc[8];
#pragma unroll
    for (int jd = 0; jd < 8; jd++)
#pragma unroll
      for (int r = 0; r < 4; r++) oacc[jd][r] = 0.f;
    float mrow[4], lrow[4];
#pragma unroll
    for (int r = 0; r < 4; r++) { mrow[r] = -INFINITY; lrow[r] = 0.f; }

#pragma unroll 1
    for (int kt = 0; kt < niter; ++kt) {
      __builtin_amdgcn_s_barrier();                      // A: prev iter fully done
#pragma unroll
      for (int c = 0; c < 2; c++) {
        int chunk = wave * 2 + c;
        int jd = chunk >> 1, k2 = chunk & 1;
        const char* src = vbase + (size_t)(jd * 16 + srow) * (Tt * 2) + kt * 128 + k2 * 64 + scol * 16;
        gload_lds16(src, VsBuf + chunk * 512);
      }
      if (kt + 1 < niter) {
#pragma unroll
        for (int c = 0; c < 2; c++) {
          int chunk = wave * 2 + c;
          int j = chunk >> 2, kc = chunk & 3;
          const char* src = kbase + (size_t)((kt + 1) * 64 + j * 16 + srow) * (Ff * 2) + kc * 64 + scol * 16;
          gload_lds16(src, KsBuf[(kt + 1) & 1] + chunk * 512);
        }
        __builtin_amdgcn_s_waitcnt(0xF74);  // vmcnt(4): K(kt) landed
      } else {
        __builtin_amdgcn_s_waitcnt(0xF72);  // vmcnt(2): K(kt) landed
      }
      __builtin_amdgcn_s_barrier();                      // B: K(kt) visible

      const __hip_bfloat16* KsB = KsBuf[kt & 1];
      const bool diag = (kt >= 2 * qi);

      f32x4 sacc[4];
#pragma unroll
      for (int j = 0; j < 4; j++)
#pragma unroll
        for (int r = 0; r < 4; r++) sacc[j][r] = 0.f;
#pragma unroll
      for (int j = 0; j < 4; j++)
#pragma unroll
        for (int kc = 0; kc < 4; kc++) {
          short8 kf = *(const short8*)(KsB + (j * 4 + kc) * 512 + lane * 8);
          sacc[j] = __builtin_amdgcn_mfma_f32_16x16x32_bf16(qf[kc], kf, sacc[j], 0, 0, 0);
        }
      float sv[4][4];
#pragma unroll
      for (int j = 0; j < 4; j++)
#pragma unroll
        for (int r = 0; r < 4; r++) {
          float v = sacc[j][r];
          if (diag) {
            int kg = kt * 64 + j * 16 + l16;
            int qg = qm0 + wave * 16 + quad * 4 + r;
            if (kg > qg) v = -INFINITY;
          }
          sv[j][r] = v;
        }
      float mnew[4];
#pragma unroll
      for (int r = 0; r < 4; r++)
        mnew[r] = fmaxf(fmaxf(sv[0][r], sv[1][r]), fmaxf(sv[2][r], sv[3][r]));
#pragma unroll
      for (int off = 1; off < 16; off <<= 1)
#pragma unroll
        for (int r = 0; r < 4; r++)
          mnew[r] = fmaxf(mnew[r], __shfl_xor(mnew[r], off, 64));
      float alpha[4];
#pragma unroll
      for (int r = 0; r < 4; r++) {
        float mi = fmaxf(mrow[r], mnew[r]);
        alpha[r] = __expf(mrow[r] - mi);
        mrow[r] = mi;
      }
      float rs[4] = {0.f, 0.f, 0.f, 0.f};
#pragma unroll
      for (int j = 0; j < 4; j++)
#pragma unroll
        for (int r = 0; r < 4; r++) {
          float p = __expf(sv[j][r] - mrow[r]);
          rs[r] += p;
          Pw[(j * 2 + (l16 >> 3)) * 136 + (quad * 4 + r) * 8 + (l16 & 7)] = __float2bfloat16(p);
        }
#pragma unroll
      for (int off = 1; off < 16; off <<= 1)
#pragma unroll
        for (int r = 0; r < 4; r++)
          rs[r] += __shfl_xor(rs[r], off, 64);
#pragma unroll
      for (int r = 0; r < 4; r++) lrow[r] = lrow[r] * alpha[r] + rs[r];
#pragma unroll
      for (int jd = 0; jd < 8; jd++)
#pragma unroll
        for (int r = 0; r < 4; r++) oacc[jd][r] *= alpha[r];

      if (kt + 1 < niter) {
        __builtin_amdgcn_s_waitcnt(0xF72);  // vmcnt(2): V(kt) landed
      } else {
        __builtin_amdgcn_s_waitcnt(0xF70);  // vmcnt(0)
      }
      __builtin_amdgcn_s_barrier();                      // C: V(kt) visible

#pragma unroll
      for (int k2 = 0; k2 < 2; k2++) {
        short8 pf = *(const short8*)(Pw + (k2 * 4 + quad) * 136 + l16 * 8);
#pragma unroll
        for (int jd = 0; jd < 8; jd++) {
          short8 vf = *(const short8*)(VsBuf + (jd * 2 + k2) * 512 + lane * 8);
          oacc[jd] = __builtin_amdgcn_mfma_f32_16x16x32_bf16(pf, vf, oacc[jd], 0, 0, 0);
        }
      }
    }

    float linv[4];
#pragma unroll
    for (int r = 0; r < 4; r++) linv[r] = 1.f / lrow[r];
#pragma unroll
    for (int jd = 0; jd < 8; jd++)
#pragma unroll
      for (int r = 0; r < 4; r++) {
        int trow = qm0 + wave * 16 + quad * 4 + r;
        yat[(size_t)(b * Tt + trow) * Cc + h * Dd + jd * 16 + l16] =
            __float2bfloat16(oacc[jd][r] * linv[r]);
      }
  }
}

extern "C" void kernel_launch(void* const* d_in, const int* in_sizes, int n_in,
                              void* d_out, int out_size, void* d_ws, size_t ws_size,
                              hipStream_t stream) {
  (void)in_sizes; (void)n_in; (void)out_size; (void)ws_size;
  const float* x_f      = (const float*)d_in[0];
  const float* w_qkv_f  = (const float*)d_in[1];
  const float* w_proj_f = (const float*)d_in[2];
  float* out = (float*)d_out;

  char* ws = (char*)d_ws;
  __hip_bfloat16* qkv = (__hip_bfloat16*)ws;                      // 48 MiB
  __hip_bfloat16* vt  = (__hip_bfloat16*)(ws + 50331648);         // 16 MiB
  __hip_bfloat16* yat = (__hip_bfloat16*)(ws + 67108864);         // 16 MiB
  __hip_bfloat16* xb  = (__hip_bfloat16*)(ws + 83886080);         // 16 MiB
  __hip_bfloat16* wqb = (__hip_bfloat16*)(ws + 100663296);        // 24 MiB
  __hip_bfloat16* wpb = (__hip_bfloat16*)(ws + 125829120);        // 8 MiB

  cast_f32_bf16<<<8192, 256, 0, stream>>>(x_f, xb, 2097152);
  cast_f32_bf16<<<12288, 256, 0, stream>>>(w_qkv_f, wqb, 3145728);
  cast_f32_bf16<<<4096, 256, 0, stream>>>(w_proj_f, wpb, 1048576);

  gemm_bt<__hip_bfloat16><<<dim3(48, 32), 256, 0, stream>>>(xb, wqb, qkv, 2048, 6144);
  rope_qk<<<32768, 256, 0, stream>>>(qkv);
  transpose_v<<<dim3(64, 32), 256, 0, stream>>>(qkv, vt);
  flash_attn3<<<256, 512, 0, stream>>>(qkv, vt, yat);
  gemm_bt<float><<<dim3(16, 32), 256, 0, stream>>>(yat, wpb, out, 2048, 2048);
}

// Round 6
// 525.937 us; speedup vs baseline: 1.0100x; 1.0100x over previous
//
#include <hip/hip_runtime.h>
#include <hip/hip_bf16.h>
#include <math.h>

typedef __attribute__((ext_vector_type(8))) short short8;
typedef __attribute__((ext_vector_type(4))) short short4_t;
typedef __attribute__((ext_vector_type(4))) float f32x4;

#define Bb 2
#define Tt 2048
#define Hh 16
#define Dd 128
#define Cc 2048
#define Ff 6144

__device__ __forceinline__ void gload_lds16(const void* g, void* l) {
  __builtin_amdgcn_global_load_lds(
      (const __attribute__((address_space(1))) void*)g,
      (__attribute__((address_space(3))) void*)l, 16, 0, 0);
}

// fp32 -> bf16 cast, 4 elements/thread, vectorized.
__global__ __launch_bounds__(256) void cast_f32_bf16(
    const float* __restrict__ in, __hip_bfloat16* __restrict__ out, int n4)
{
  int i = blockIdx.x * 256 + threadIdx.x;
  if (i >= n4) return;
  float4 v = ((const float4*)in)[i];
  __hip_bfloat16 tmp[4] = {__float2bfloat16(v.x), __float2bfloat16(v.y),
                           __float2bfloat16(v.z), __float2bfloat16(v.w)};
  ((short4_t*)out)[i] = *(const short4_t*)tmp;
}

__device__ __forceinline__ void store_out(__hip_bfloat16* p, float v) { *p = __float2bfloat16(v); }
__device__ __forceinline__ void store_out(float* p, float v) { *p = v; }

// C (MxN) = A (MxK row-major) * B^T (B NxK row-major). bf16 in, fp32 accum.
// 128x128x32 tile (BK=32: 16 KB LDS -> 8 blocks/CU, the proven round-4 occupancy)
// with fragment-granule LDS layout (round-5's zero-conflict reads):
// granule g (0..7) = rows g*16..+15, full 32-col k-slab; lane l of the staging
// wave writes [scol=l>>4][srow=l&15] 16B, so MFMA fragment reads are
// granule_base + lane*16B -> conflict-free ds_read_b128.
template <typename OutT>
__global__ __launch_bounds__(256) void gemm_bt(
    const __hip_bfloat16* __restrict__ A,
    const __hip_bfloat16* __restrict__ Bm,
    OutT* __restrict__ Cm,
    int K, int N)
{
  __shared__ __align__(16) __hip_bfloat16 As[128 * 32];
  __shared__ __align__(16) __hip_bfloat16 Bs[128 * 32];
  const int tid  = threadIdx.x;
  const int wave = tid >> 6;
  const int lane = tid & 63;
  const int quad = lane >> 4;
  const int l16  = lane & 15;
  const int bm = blockIdx.y * 128;
  const int bn = blockIdx.x * 128;
  const int wm4 = (wave >> 1) * 4;   // granule base of this wave's M range
  const int wn4 = (wave & 1) * 4;    // granule base of this wave's N range

  f32x4 acc[4][4];
#pragma unroll
  for (int i = 0; i < 4; i++)
#pragma unroll
    for (int j = 0; j < 4; j++)
#pragma unroll
      for (int r = 0; r < 4; r++) acc[i][j][r] = 0.f;

  const int srow = lane & 15;   // staging: row within 16-row granule
  const int scol = lane >> 4;   // staging: 16B sub-column (0..3)

  // Hoisted staging pointers: this wave stages granules wave*2, wave*2+1 of A and B.
  const char* pA[2];
  const char* pB[2];
#pragma unroll
  for (int c = 0; c < 2; c++) {
    int g = wave * 2 + c;
    pA[c] = (const char*)A  + ((size_t)(bm + g * 16 + srow) * K + scol * 8) * 2;
    pB[c] = (const char*)Bm + ((size_t)(bn + g * 16 + srow) * K + scol * 8) * 2;
  }

  for (int k0 = 0; k0 < K; k0 += 32) {
#pragma unroll
    for (int c = 0; c < 2; c++) {
      int g = wave * 2 + c;  // wave-uniform granule id
      gload_lds16(pA[c], As + g * 512);
      gload_lds16(pB[c], Bs + g * 512);
      pA[c] += 64;
      pB[c] += 64;
    }
    __syncthreads();
    short8 af[4], bf[4];
#pragma unroll
    for (int i = 0; i < 4; i++)
      af[i] = *(const short8*)(As + (wm4 + i) * 512 + lane * 8);
#pragma unroll
    for (int j = 0; j < 4; j++)
      bf[j] = *(const short8*)(Bs + (wn4 + j) * 512 + lane * 8);
#pragma unroll
    for (int i = 0; i < 4; i++)
#pragma unroll
      for (int j = 0; j < 4; j++)
        acc[i][j] = __builtin_amdgcn_mfma_f32_16x16x32_bf16(af[i], bf[j], acc[i][j], 0, 0, 0);
    __syncthreads();
  }

#pragma unroll
  for (int i = 0; i < 4; i++)
#pragma unroll
    for (int j = 0; j < 4; j++)
#pragma unroll
      for (int r = 0; r < 4; r++) {
        int gm = bm + (wave >> 1) * 64 + i * 16 + quad * 4 + r;
        int gn = bn + (wave & 1) * 64 + j * 16 + l16;
        store_out(Cm + (size_t)gm * N + gn, acc[i][j][r]);
      }
}

// In-place RoPE on q,k halves of qkv. Q half additionally pre-scaled by 1/sqrt(D)
// so the flash kernel needs no per-score multiply.
__global__ __launch_bounds__(256) void rope_qk(__hip_bfloat16* __restrict__ qkv)
{
  int tid = blockIdx.x * 256 + threadIdx.x;
  int d = tid & 63;
  int h = (tid >> 6) & 15;
  int t = (tid >> 10) & 2047;
  int bw = tid >> 21;
  int b = bw & 1, which = bw >> 1;
  size_t base = (size_t)(b * Tt + t) * Ff + which * 2048 + h * Dd + d;
  float inv = expf(-(float)d * (9.210340371976184f / 64.0f));
  float ang = (float)t * inv;
  float c = cosf(ang), s = sinf(ang);
  float x1 = __bfloat162float(qkv[base]);
  float x2 = __bfloat162float(qkv[base + 64]);
  float o1 = x1 * c - x2 * s;
  float o2 = x2 * c + x1 * s;
  if (which == 0) {  // q: fold in softmax scale
    o1 *= 0.08838834764831845f;
    o2 *= 0.08838834764831845f;
  }
  qkv[base]      = __float2bfloat16(o1);
  qkv[base + 64] = __float2bfloat16(o2);
}

// v (from qkv buffer, (b,t,h,d)) -> vt (b,h,d,t).
__global__ __launch_bounds__(256) void transpose_v(
    const __hip_bfloat16* __restrict__ qkv, __hip_bfloat16* __restrict__ vt)
{
  __shared__ __hip_bfloat16 tile[64 * 65];
  int bh = blockIdx.y;
  int dt = blockIdx.x >> 5;
  int tt = blockIdx.x & 31;
  int b = bh >> 4, h = bh & 15;
  const __hip_bfloat16* src = qkv + (size_t)(b * Tt + tt * 64) * Ff + 4096 + h * Dd + dt * 64;
#pragma unroll
  for (int i = 0; i < 16; i++) {
    int lin = i * 256 + threadIdx.x;
    int tl = lin >> 6, dc = lin & 63;
    tile[tl * 65 + dc] = src[(size_t)tl * Ff + dc];
  }
  __syncthreads();
  __hip_bfloat16* dst = vt + ((size_t)bh * Dd + dt * 64) * Tt + tt * 64;
#pragma unroll
  for (int i = 0; i < 16; i++) {
    int lin = i * 256 + threadIdx.x;
    int dr = lin >> 6, tc = lin & 63;
    dst[(size_t)dr * Tt + tc] = tile[tc * 65 + dr];
  }
}

// Flash attention v3: 512 threads (8 waves, 16 q-rows each -> 2 waves/SIMD),
// 128-row Q tiles, paired causal scheduling {p, 15-p}, software-pipelined
// staging with raw s_barrier + manual vmcnt.
__global__ __launch_bounds__(512) void flash_attn3(
    const __hip_bfloat16* __restrict__ qkv,
    const __hip_bfloat16* __restrict__ vt,
    __hip_bfloat16* __restrict__ yat)
{
  __shared__ __align__(16) __hip_bfloat16 KsBuf[2][8192];
  __shared__ __align__(16) __hip_bfloat16 VsBuf[8192];
  __shared__ __align__(16) __hip_bfloat16 PsBuf[8 * 1088];
  const int tid  = threadIdx.x;
  const int wave = tid >> 6;          // 0..7
  const int lane = tid & 63;
  const int quad = lane >> 4;
  const int l16  = lane & 15;
  const int bh    = blockIdx.x & 31;
  const int pairp = blockIdx.x >> 5;  // 0..7
  const int b = bh >> 4, h = bh & 15;

  const char* kbase = (const char*)(qkv + (size_t)b * Tt * Ff + 2048 + h * Dd);
  const char* vbase = (const char*)(vt + (size_t)bh * Dd * Tt);
  __hip_bfloat16* Pw = PsBuf + wave * 1088;
  const int srow = lane & 15;
  const int scol = lane >> 4;

#pragma unroll 1
  for (int half = 0; half < 2; ++half) {
    const int qi = half ? (15 - pairp) : pairp;
    const int qm0 = qi * 128;
    const int niter = 2 * qi + 2;

    short8 qf[4];
    {
      const __hip_bfloat16* qrow =
          qkv + (size_t)(b * Tt + qm0 + wave * 16 + l16) * Ff + h * Dd;
#pragma unroll
      for (int kc = 0; kc < 4; kc++)
        qf[kc] = *(const short8*)(qrow + kc * 32 + quad * 8);
    }

#pragma unroll
    for (int c = 0; c < 2; c++) {
      int chunk = wave * 2 + c;
      int j = chunk >> 2, kc = chunk & 3;
      const char* src = kbase + (size_t)(j * 16 + srow) * (Ff * 2) + kc * 64 + scol * 16;
      gload_lds16(src, KsBuf[0] + chunk * 512);
    }

    f32x4 oacc[8];
#pragma unroll
    for (int jd = 0; jd < 8; jd++)
#pragma unroll
      for (int r = 0; r < 4; r++) oacc[jd][r] = 0.f;
    float mrow[4], lrow[4];
#pragma unroll
    for (int r = 0; r < 4; r++) { mrow[r] = -INFINITY; lrow[r] = 0.f; }

#pragma unroll 1
    for (int kt = 0; kt < niter; ++kt) {
      __builtin_amdgcn_s_barrier();                      // A: prev iter fully done
#pragma unroll
      for (int c = 0; c < 2; c++) {
        int chunk = wave * 2 + c;
        int jd = chunk >> 1, k2 = chunk & 1;
        const char* src = vbase + (size_t)(jd * 16 + srow) * (Tt * 2) + kt * 128 + k2 * 64 + scol * 16;
        gload_lds16(src, VsBuf + chunk * 512);
      }
      if (kt + 1 < niter) {
#pragma unroll
        for (int c = 0; c < 2; c++) {
          int chunk = wave * 2 + c;
          int j = chunk >> 2, kc = chunk & 3;
          const char* src = kbase + (size_t)((kt + 1) * 64 + j * 16 + srow) * (Ff * 2) + kc * 64 + scol * 16;
          gload_lds16(src, KsBuf[(kt + 1) & 1] + chunk * 512);
        }
        __builtin_amdgcn_s_waitcnt(0xF74);  // vmcnt(4): K(kt) landed
      } else {
        __builtin_amdgcn_s_waitcnt(0xF72);  // vmcnt(2): K(kt) landed
      }
      __builtin_amdgcn_s_barrier();                      // B: K(kt) visible

      const __hip_bfloat16* KsB = KsBuf[kt & 1];
      const bool diag = (kt >= 2 * qi);

      f32x4 sacc[4];
#pragma unroll
      for (int j = 0; j < 4; j++)
#pragma unroll
        for (int r = 0; r < 4; r++) sacc[j][r] = 0.f;
#pragma unroll
      for (int j = 0; j < 4; j++)
#pragma unroll
        for (int kc = 0; kc < 4; kc++) {
          short8 kf = *(const short8*)(KsB + (j * 4 + kc) * 512 + lane * 8);
          sacc[j] = __builtin_amdgcn_mfma_f32_16x16x32_bf16(qf[kc], kf, sacc[j], 0, 0, 0);
        }
      float sv[4][4];
#pragma unroll
      for (int j = 0; j < 4; j++)
#pragma unroll
        for (int r = 0; r < 4; r++) {
          float v = sacc[j][r];
          if (diag) {
            int kg = kt * 64 + j * 16 + l16;
            int qg = qm0 + wave * 16 + quad * 4 + r;
            if (kg > qg) v = -INFINITY;
          }
          sv[j][r] = v;
        }
      float mnew[4];
#pragma unroll
      for (int r = 0; r < 4; r++)
        mnew[r] = fmaxf(fmaxf(sv[0][r], sv[1][r]), fmaxf(sv[2][r], sv[3][r]));
#pragma unroll
      for (int off = 1; off < 16; off <<= 1)
#pragma unroll
        for (int r = 0; r < 4; r++)
          mnew[r] = fmaxf(mnew[r], __shfl_xor(mnew[r], off, 64));
      float alpha[4];
#pragma unroll
      for (int r = 0; r < 4; r++) {
        float mi = fmaxf(mrow[r], mnew[r]);
        alpha[r] = __expf(mrow[r] - mi);
        mrow[r] = mi;
      }
      float rs[4] = {0.f, 0.f, 0.f, 0.f};
#pragma unroll
      for (int j = 0; j < 4; j++)
#pragma unroll
        for (int r = 0; r < 4; r++) {
          float p = __expf(sv[j][r] - mrow[r]);
          rs[r] += p;
          Pw[(j * 2 + (l16 >> 3)) * 136 + (quad * 4 + r) * 8 + (l16 & 7)] = __float2bfloat16(p);
        }
#pragma unroll
      for (int off = 1; off < 16; off <<= 1)
#pragma unroll
        for (int r = 0; r < 4; r++)
          rs[r] += __shfl_xor(rs[r], off, 64);
#pragma unroll
      for (int r = 0; r < 4; r++) lrow[r] = lrow[r] * alpha[r] + rs[r];
#pragma unroll
      for (int jd = 0; jd < 8; jd++)
#pragma unroll
        for (int r = 0; r < 4; r++) oacc[jd][r] *= alpha[r];

      if (kt + 1 < niter) {
        __builtin_amdgcn_s_waitcnt(0xF72);  // vmcnt(2): V(kt) landed
      } else {
        __builtin_amdgcn_s_waitcnt(0xF70);  // vmcnt(0)
      }
      __builtin_amdgcn_s_barrier();                      // C: V(kt) visible

#pragma unroll
      for (int k2 = 0; k2 < 2; k2++) {
        short8 pf = *(const short8*)(Pw + (k2 * 4 + quad) * 136 + l16 * 8);
#pragma unroll
        for (int jd = 0; jd < 8; jd++) {
          short8 vf = *(const short8*)(VsBuf + (jd * 2 + k2) * 512 + lane * 8);
          oacc[jd] = __builtin_amdgcn_mfma_f32_16x16x32_bf16(pf, vf, oacc[jd], 0, 0, 0);
        }
      }
    }

    float linv[4];
#pragma unroll
    for (int r = 0; r < 4; r++) linv[r] = 1.f / lrow[r];
#pragma unroll
    for (int jd = 0; jd < 8; jd++)
#pragma unroll
      for (int r = 0; r < 4; r++) {
        int trow = qm0 + wave * 16 + quad * 4 + r;
        yat[(size_t)(b * Tt + trow) * Cc + h * Dd + jd * 16 + l16] =
            __float2bfloat16(oacc[jd][r] * linv[r]);
      }
  }
}

extern "C" void kernel_launch(void* const* d_in, const int* in_sizes, int n_in,
                              void* d_out, int out_size, void* d_ws, size_t ws_size,
                              hipStream_t stream) {
  (void)in_sizes; (void)n_in; (void)out_size; (void)ws_size;
  const float* x_f      = (const float*)d_in[0];
  const float* w_qkv_f  = (const float*)d_in[1];
  const float* w_proj_f = (const float*)d_in[2];
  float* out = (float*)d_out;

  char* ws = (char*)d_ws;
  __hip_bfloat16* qkv = (__hip_bfloat16*)ws;                      // 48 MiB
  __hip_bfloat16* vt  = (__hip_bfloat16*)(ws + 50331648);         // 16 MiB
  __hip_bfloat16* yat = (__hip_bfloat16*)(ws + 67108864);         // 16 MiB
  __hip_bfloat16* xb  = (__hip_bfloat16*)(ws + 83886080);         // 16 MiB
  __hip_bfloat16* wqb = (__hip_bfloat16*)(ws + 100663296);        // 24 MiB
  __hip_bfloat16* wpb = (__hip_bfloat16*)(ws + 125829120);        // 8 MiB

  cast_f32_bf16<<<8192, 256, 0, stream>>>(x_f, xb, 2097152);
  cast_f32_bf16<<<12288, 256, 0, stream>>>(w_qkv_f, wqb, 3145728);
  cast_f32_bf16<<<4096, 256, 0, stream>>>(w_proj_f, wpb, 1048576);

  gemm_bt<__hip_bfloat16><<<dim3(48, 32), 256, 0, stream>>>(xb, wqb, qkv, 2048, 6144);
  rope_qk<<<32768, 256, 0, stream>>>(qkv);
  transpose_v<<<dim3(64, 32), 256, 0, stream>>>(qkv, vt);
  flash_attn3<<<256, 512, 0, stream>>>(qkv, vt, yat);
  gemm_bt<float><<<dim3(16, 32), 256, 0, stream>>>(yat, wpb, out, 2048, 2048);
}

// Round 7
// 454.328 us; speedup vs baseline: 1.1692x; 1.1576x over previous
//
#include <hip/hip_runtime.h>
#include <hip/hip_bf16.h>
#include <math.h>

typedef __attribute__((ext_vector_type(8))) short short8;
typedef __attribute__((ext_vector_type(4))) short short4_t;
typedef __attribute__((ext_vector_type(4))) float f32x4;

#define Bb 2
#define Tt 2048
#define Hh 16
#define Dd 128
#define Cc 2048
#define Ff 6144

// Packed operand layout (K=2048 only): element (row,k) lives at
//   ((m_tile*64 + ks)*8 + g)*512 + (sub*16 + srow)*8 + w
// where m_tile=row>>7, g=(row>>4)&7, srow=row&15, ks=k>>5, sub=(k>>3)&3, w=k&7.
// Each 1024B granule is exactly one global_load_lds: lane l reads byte l*16 and
// LDS-writes byte l*16, giving A[g*16+(l&15)][(l>>4)*8..+7] — the MFMA fragment
// order — so staging is fully coalesced AND fragment ds_read_b128 is conflict-free.
__device__ __forceinline__ size_t packed_idx(int row, int k) {
  return ((((size_t)(row >> 7) * 64 + (k >> 5)) * 8 + ((row >> 4) & 7)) * 512)
         + ((((k >> 3) & 3) * 16 + (row & 15)) * 8) + (k & 7);
}

__device__ __forceinline__ void gload_lds16(const void* g, void* l) {
  __builtin_amdgcn_global_load_lds(
      (const __attribute__((address_space(1))) void*)g,
      (__attribute__((address_space(3))) void*)l, 16, 0, 0);
}

// fp32 row-major (rows x 2048) -> bf16 packed layout. One thread per 16B output
// chunk (8 elements); writes coalesced, reads 16 x 128B segments per wave.
__global__ __launch_bounds__(256) void pack_cast(
    const float* __restrict__ in, __hip_bfloat16* __restrict__ out, int n16)
{
  int t = blockIdx.x * 256 + threadIdx.x;
  if (t >= n16) return;
  int l = t & 63;
  int granule_lin = t >> 6;
  int g = granule_lin & 7;
  int slab = granule_lin >> 3;
  int ks = slab & 63;          // K/32 = 64
  int m_tile = slab >> 6;
  int row = m_tile * 128 + g * 16 + (l & 15);
  int k = ks * 32 + (l >> 4) * 8;
  const float* src = in + (size_t)row * 2048 + k;
  float4 v0 = *(const float4*)src;
  float4 v1 = *(const float4*)(src + 4);
  __hip_bfloat16 tmp[8] = {
      __float2bfloat16(v0.x), __float2bfloat16(v0.y),
      __float2bfloat16(v0.z), __float2bfloat16(v0.w),
      __float2bfloat16(v1.x), __float2bfloat16(v1.y),
      __float2bfloat16(v1.z), __float2bfloat16(v1.w)};
  *(short8*)(out + (size_t)t * 8) = *(const short8*)tmp;
}

__device__ __forceinline__ void store_out(__hip_bfloat16* p, float v) { *p = __float2bfloat16(v); }
__device__ __forceinline__ void store_out(float* p, float v) { *p = v; }

// C (MxN row-major) = A * B^T with A (MxK), B (NxK) BOTH in packed layout above.
// 128x128x32 tile, 16 KB LDS (8 blocks/CU), granule LDS layout: staging loads
// are 1KB contiguous, fragment reads conflict-free.
template <typename OutT>
__global__ __launch_bounds__(256) void gemm_pk(
    const __hip_bfloat16* __restrict__ Ap,
    const __hip_bfloat16* __restrict__ Bp,
    OutT* __restrict__ Cm,
    int K, int N)
{
  __shared__ __align__(16) __hip_bfloat16 As[128 * 32];
  __shared__ __align__(16) __hip_bfloat16 Bs[128 * 32];
  const int tid  = threadIdx.x;
  const int wave = tid >> 6;
  const int lane = tid & 63;
  const int quad = lane >> 4;
  const int l16  = lane & 15;
  const int bm = blockIdx.y * 128;
  const int bn = blockIdx.x * 128;
  const int wm4 = (wave >> 1) * 4;   // granule base of this wave's M range
  const int wn4 = (wave & 1) * 4;    // granule base of this wave's N range
  const int KS = K >> 5;

  f32x4 acc[4][4];
#pragma unroll
  for (int i = 0; i < 4; i++)
#pragma unroll
    for (int j = 0; j < 4; j++)
#pragma unroll
      for (int r = 0; r < 4; r++) acc[i][j][r] = 0.f;

  // Hoisted staging pointers: wave stages granules wave*2, wave*2+1 (1KB each,
  // contiguous: lane l reads byte l*16).
  const char* pA[2];
  const char* pB[2];
#pragma unroll
  for (int c = 0; c < 2; c++) {
    int g = wave * 2 + c;
    pA[c] = (const char*)Ap + (size_t)(bm >> 7) * KS * 8192 + g * 1024 + lane * 16;
    pB[c] = (const char*)Bp + (size_t)(bn >> 7) * KS * 8192 + g * 1024 + lane * 16;
  }

  for (int ks = 0; ks < KS; ks++) {
#pragma unroll
    for (int c = 0; c < 2; c++) {
      int g = wave * 2 + c;  // wave-uniform granule id
      gload_lds16(pA[c], As + g * 512);
      gload_lds16(pB[c], Bs + g * 512);
      pA[c] += 8192;
      pB[c] += 8192;
    }
    __syncthreads();
    short8 af[4], bf[4];
#pragma unroll
    for (int i = 0; i < 4; i++)
      af[i] = *(const short8*)(As + (wm4 + i) * 512 + lane * 8);
#pragma unroll
    for (int j = 0; j < 4; j++)
      bf[j] = *(const short8*)(Bs + (wn4 + j) * 512 + lane * 8);
#pragma unroll
    for (int i = 0; i < 4; i++)
#pragma unroll
      for (int j = 0; j < 4; j++)
        acc[i][j] = __builtin_amdgcn_mfma_f32_16x16x32_bf16(af[i], bf[j], acc[i][j], 0, 0, 0);
    __syncthreads();
  }

#pragma unroll
  for (int i = 0; i < 4; i++)
#pragma unroll
    for (int j = 0; j < 4; j++)
#pragma unroll
      for (int r = 0; r < 4; r++) {
        int gm = bm + (wave >> 1) * 64 + i * 16 + quad * 4 + r;
        int gn = bn + (wave & 1) * 64 + j * 16 + l16;
        store_out(Cm + (size_t)gm * N + gn, acc[i][j][r]);
      }
}

// In-place RoPE on q,k halves of qkv. Q half additionally pre-scaled by 1/sqrt(D).
__global__ __launch_bounds__(256) void rope_qk(__hip_bfloat16* __restrict__ qkv)
{
  int tid = blockIdx.x * 256 + threadIdx.x;
  int d = tid & 63;
  int h = (tid >> 6) & 15;
  int t = (tid >> 10) & 2047;
  int bw = tid >> 21;
  int b = bw & 1, which = bw >> 1;
  size_t base = (size_t)(b * Tt + t) * Ff + which * 2048 + h * Dd + d;
  float inv = expf(-(float)d * (9.210340371976184f / 64.0f));
  float ang = (float)t * inv;
  float c = cosf(ang), s = sinf(ang);
  float x1 = __bfloat162float(qkv[base]);
  float x2 = __bfloat162float(qkv[base + 64]);
  float o1 = x1 * c - x2 * s;
  float o2 = x2 * c + x1 * s;
  if (which == 0) {
    o1 *= 0.08838834764831845f;
    o2 *= 0.08838834764831845f;
  }
  qkv[base]      = __float2bfloat16(o1);
  qkv[base + 64] = __float2bfloat16(o2);
}

// v (from qkv buffer, (b,t,h,d)) -> vt (b,h,d,t).
__global__ __launch_bounds__(256) void transpose_v(
    const __hip_bfloat16* __restrict__ qkv, __hip_bfloat16* __restrict__ vt)
{
  __shared__ __hip_bfloat16 tile[64 * 65];
  int bh = blockIdx.y;
  int dt = blockIdx.x >> 5;
  int tt = blockIdx.x & 31;
  int b = bh >> 4, h = bh & 15;
  const __hip_bfloat16* src = qkv + (size_t)(b * Tt + tt * 64) * Ff + 4096 + h * Dd + dt * 64;
#pragma unroll
  for (int i = 0; i < 16; i++) {
    int lin = i * 256 + threadIdx.x;
    int tl = lin >> 6, dc = lin & 63;
    tile[tl * 65 + dc] = src[(size_t)tl * Ff + dc];
  }
  __syncthreads();
  __hip_bfloat16* dst = vt + ((size_t)bh * Dd + dt * 64) * Tt + tt * 64;
#pragma unroll
  for (int i = 0; i < 16; i++) {
    int lin = i * 256 + threadIdx.x;
    int dr = lin >> 6, tc = lin & 63;
    dst[(size_t)dr * Tt + tc] = tile[tc * 65 + dr];
  }
}

// Flash attention v3: 512 threads (8 waves, 16 q-rows each), 128-row Q tiles,
// paired causal scheduling {p, 15-p}, software-pipelined staging. Epilogue
// writes yat in PACKED layout (consumed by gemm_pk for the projection).
__global__ __launch_bounds__(512) void flash_attn3(
    const __hip_bfloat16* __restrict__ qkv,
    const __hip_bfloat16* __restrict__ vt,
    __hip_bfloat16* __restrict__ yat)
{
  __shared__ __align__(16) __hip_bfloat16 KsBuf[2][8192];
  __shared__ __align__(16) __hip_bfloat16 VsBuf[8192];
  __shared__ __align__(16) __hip_bfloat16 PsBuf[8 * 1088];
  const int tid  = threadIdx.x;
  const int wave = tid >> 6;          // 0..7
  const int lane = tid & 63;
  const int quad = lane >> 4;
  const int l16  = lane & 15;
  const int bh    = blockIdx.x & 31;
  const int pairp = blockIdx.x >> 5;  // 0..7
  const int b = bh >> 4, h = bh & 15;

  const char* kbase = (const char*)(qkv + (size_t)b * Tt * Ff + 2048 + h * Dd);
  const char* vbase = (const char*)(vt + (size_t)bh * Dd * Tt);
  __hip_bfloat16* Pw = PsBuf + wave * 1088;
  const int srow = lane & 15;
  const int scol = lane >> 4;

#pragma unroll 1
  for (int half = 0; half < 2; ++half) {
    const int qi = half ? (15 - pairp) : pairp;
    const int qm0 = qi * 128;
    const int niter = 2 * qi + 2;

    short8 qf[4];
    {
      const __hip_bfloat16* qrow =
          qkv + (size_t)(b * Tt + qm0 + wave * 16 + l16) * Ff + h * Dd;
#pragma unroll
      for (int kc = 0; kc < 4; kc++)
        qf[kc] = *(const short8*)(qrow + kc * 32 + quad * 8);
    }

#pragma unroll
    for (int c = 0; c < 2; c++) {
      int chunk = wave * 2 + c;
      int j = chunk >> 2, kc = chunk & 3;
      const char* src = kbase + (size_t)(j * 16 + srow) * (Ff * 2) + kc * 64 + scol * 16;
      gload_lds16(src, KsBuf[0] + chunk * 512);
    }

    f32x4 oacc[8];
#pragma unroll
    for (int jd = 0; jd < 8; jd++)
#pragma unroll
      for (int r = 0; r < 4; r++) oacc[jd][r] = 0.f;
    float mrow[4], lrow[4];
#pragma unroll
    for (int r = 0; r < 4; r++) { mrow[r] = -INFINITY; lrow[r] = 0.f; }

#pragma unroll 1
    for (int kt = 0; kt < niter; ++kt) {
      __builtin_amdgcn_s_barrier();                      // A: prev iter fully done
#pragma unroll
      for (int c = 0; c < 2; c++) {
        int chunk = wave * 2 + c;
        int jd = chunk >> 1, k2 = chunk & 1;
        const char* src = vbase + (size_t)(jd * 16 + srow) * (Tt * 2) + kt * 128 + k2 * 64 + scol * 16;
        gload_lds16(src, VsBuf + chunk * 512);
      }
      if (kt + 1 < niter) {
#pragma unroll
        for (int c = 0; c < 2; c++) {
          int chunk = wave * 2 + c;
          int j = chunk >> 2, kc = chunk & 3;
          const char* src = kbase + (size_t)((kt + 1) * 64 + j * 16 + srow) * (Ff * 2) + kc * 64 + scol * 16;
          gload_lds16(src, KsBuf[(kt + 1) & 1] + chunk * 512);
        }
        __builtin_amdgcn_s_waitcnt(0xF74);  // vmcnt(4): K(kt) landed
      } else {
        __builtin_amdgcn_s_waitcnt(0xF72);  // vmcnt(2): K(kt) landed
      }
      __builtin_amdgcn_s_barrier();                      // B: K(kt) visible

      const __hip_bfloat16* KsB = KsBuf[kt & 1];
      const bool diag = (kt >= 2 * qi);

      f32x4 sacc[4];
#pragma unroll
      for (int j = 0; j < 4; j++)
#pragma unroll
        for (int r = 0; r < 4; r++) sacc[j][r] = 0.f;
#pragma unroll
      for (int j = 0; j < 4; j++)
#pragma unroll
        for (int kc = 0; kc < 4; kc++) {
          short8 kf = *(const short8*)(KsB + (j * 4 + kc) * 512 + lane * 8);
          sacc[j] = __builtin_amdgcn_mfma_f32_16x16x32_bf16(qf[kc], kf, sacc[j], 0, 0, 0);
        }
      float sv[4][4];
#pragma unroll
      for (int j = 0; j < 4; j++)
#pragma unroll
        for (int r = 0; r < 4; r++) {
          float v = sacc[j][r];
          if (diag) {
            int kg = kt * 64 + j * 16 + l16;
            int qg = qm0 + wave * 16 + quad * 4 + r;
            if (kg > qg) v = -INFINITY;
          }
          sv[j][r] = v;
        }
      float mnew[4];
#pragma unroll
      for (int r = 0; r < 4; r++)
        mnew[r] = fmaxf(fmaxf(sv[0][r], sv[1][r]), fmaxf(sv[2][r], sv[3][r]));
#pragma unroll
      for (int off = 1; off < 16; off <<= 1)
#pragma unroll
        for (int r = 0; r < 4; r++)
          mnew[r] = fmaxf(mnew[r], __shfl_xor(mnew[r], off, 64));
      float alpha[4];
#pragma unroll
      for (int r = 0; r < 4; r++) {
        float mi = fmaxf(mrow[r], mnew[r]);
        alpha[r] = __expf(mrow[r] - mi);
        mrow[r] = mi;
      }
      float rs[4] = {0.f, 0.f, 0.f, 0.f};
#pragma unroll
      for (int j = 0; j < 4; j++)
#pragma unroll
        for (int r = 0; r < 4; r++) {
          float p = __expf(sv[j][r] - mrow[r]);
          rs[r] += p;
          Pw[(j * 2 + (l16 >> 3)) * 136 + (quad * 4 + r) * 8 + (l16 & 7)] = __float2bfloat16(p);
        }
#pragma unroll
      for (int off = 1; off < 16; off <<= 1)
#pragma unroll
        for (int r = 0; r < 4; r++)
          rs[r] += __shfl_xor(rs[r], off, 64);
#pragma unroll
      for (int r = 0; r < 4; r++) lrow[r] = lrow[r] * alpha[r] + rs[r];
#pragma unroll
      for (int jd = 0; jd < 8; jd++)
#pragma unroll
        for (int r = 0; r < 4; r++) oacc[jd][r] *= alpha[r];

      if (kt + 1 < niter) {
        __builtin_amdgcn_s_waitcnt(0xF72);  // vmcnt(2): V(kt) landed
      } else {
        __builtin_amdgcn_s_waitcnt(0xF70);  // vmcnt(0)
      }
      __builtin_amdgcn_s_barrier();                      // C: V(kt) visible

#pragma unroll
      for (int k2 = 0; k2 < 2; k2++) {
        short8 pf = *(const short8*)(Pw + (k2 * 4 + quad) * 136 + l16 * 8);
#pragma unroll
        for (int jd = 0; jd < 8; jd++) {
          short8 vf = *(const short8*)(VsBuf + (jd * 2 + k2) * 512 + lane * 8);
          oacc[jd] = __builtin_amdgcn_mfma_f32_16x16x32_bf16(pf, vf, oacc[jd], 0, 0, 0);
        }
      }
    }

    // epilogue: O / l -> yat in PACKED layout (A-operand of projection GEMM)
    float linv[4];
#pragma unroll
    for (int r = 0; r < 4; r++) linv[r] = 1.f / lrow[r];
#pragma unroll
    for (int jd = 0; jd < 8; jd++)
#pragma unroll
      for (int r = 0; r < 4; r++) {
        int row = b * Tt + qm0 + wave * 16 + quad * 4 + r;
        int c = h * Dd + jd * 16 + l16;
        yat[packed_idx(row, c)] = __float2bfloat16(oacc[jd][r] * linv[r]);
      }
  }
}

extern "C" void kernel_launch(void* const* d_in, const int* in_sizes, int n_in,
                              void* d_out, int out_size, void* d_ws, size_t ws_size,
                              hipStream_t stream) {
  (void)in_sizes; (void)n_in; (void)out_size; (void)ws_size;
  const float* x_f      = (const float*)d_in[0];
  const float* w_qkv_f  = (const float*)d_in[1];
  const float* w_proj_f = (const float*)d_in[2];
  float* out = (float*)d_out;

  char* ws = (char*)d_ws;
  __hip_bfloat16* qkv = (__hip_bfloat16*)ws;                      // 48 MiB
  __hip_bfloat16* vt  = (__hip_bfloat16*)(ws + 50331648);         // 16 MiB
  __hip_bfloat16* yat = (__hip_bfloat16*)(ws + 67108864);         // 16 MiB (packed)
  __hip_bfloat16* xb  = (__hip_bfloat16*)(ws + 83886080);         // 16 MiB (packed)
  __hip_bfloat16* wqb = (__hip_bfloat16*)(ws + 100663296);        // 24 MiB (packed)
  __hip_bfloat16* wpb = (__hip_bfloat16*)(ws + 125829120);        // 8 MiB (packed)

  // pack-cast fp32 inputs -> bf16 packed tiles (K=2048 for all three)
  pack_cast<<<4096, 256, 0, stream>>>(x_f, xb, 1048576);       // 4096 x 2048
  pack_cast<<<6144, 256, 0, stream>>>(w_qkv_f, wqb, 1572864);  // 6144 x 2048
  pack_cast<<<2048, 256, 0, stream>>>(w_proj_f, wpb, 524288);  // 2048 x 2048

  gemm_pk<__hip_bfloat16><<<dim3(48, 32), 256, 0, stream>>>(xb, wqb, qkv, 2048, 6144);
  rope_qk<<<32768, 256, 0, stream>>>(qkv);
  transpose_v<<<dim3(64, 32), 256, 0, stream>>>(qkv, vt);
  flash_attn3<<<256, 512, 0, stream>>>(qkv, vt, yat);
  gemm_pk<float><<<dim3(16, 32), 256, 0, stream>>>(yat, wpb, out, 2048, 2048);
}